// Round 1
// baseline (1900.766 us; speedup 1.0000x reference)
//
#include <hip/hip_runtime.h>
#include <hip/hip_bf16.h>

#define NN 50000
#define NE 600000
#define HIDC 128
#define NH 8
#define DH 16

typedef unsigned short u16;

static __device__ __forceinline__ float bf2f(u16 u) {
    unsigned int x = ((unsigned int)u) << 16;
    return __uint_as_float(x);
}
static __device__ __forceinline__ u16 f2bf(float f) {
    unsigned int x = __float_as_uint(f);
    unsigned int r = (x + 0x7fffu + ((x >> 16) & 1u)) >> 16;
    return (u16)r;
}

// ---------------- CSR build ----------------
__global__ void k_init(int* deg, int* cursor) {
    int i = blockIdx.x * blockDim.x + threadIdx.x;
    if (i < NN) { deg[i] = 0; cursor[i] = 0; }
}

__global__ void k_count(const int* __restrict__ ei, int* __restrict__ deg) {
    int e = blockIdx.x * blockDim.x + threadIdx.x;
    if (e < NE) atomicAdd(&deg[ei[e]], 1);
}

__global__ void k_scan(const int* __restrict__ deg, int* __restrict__ rowstart) {
    __shared__ int buf[1024];
    __shared__ int carry_s;
    int t = threadIdx.x;
    if (t == 0) { rowstart[0] = 0; carry_s = 0; }
    __syncthreads();
    for (int base = 0; base < NN; base += 1024) {
        int v = (base + t < NN) ? deg[base + t] : 0;
        buf[t] = v;
        __syncthreads();
        for (int off = 1; off < 1024; off <<= 1) {
            int add = (t >= off) ? buf[t - off] : 0;
            __syncthreads();
            buf[t] += add;
            __syncthreads();
        }
        int carryv = carry_s;
        if (base + t < NN) rowstart[base + t + 1] = carryv + buf[t];
        __syncthreads();
        if (t == 0) carry_s = carryv + buf[1023];
        __syncthreads();
    }
}

__global__ void k_fill(const int* __restrict__ ei, const int* __restrict__ rowstart,
                       int* __restrict__ cursor, int* __restrict__ csr) {
    int e = blockIdx.x * blockDim.x + threadIdx.x;
    if (e < NE) {
        int d = ei[e];
        int slot = atomicAdd(&cursor[d], 1);
        csr[rowstart[d] + slot] = e;
    }
}

// ---------------- generic fp32 GEMM: C[M x NC] = A[M x K] @ W[K x NC] (+bias)(+relu)
// 64 rows per block, full NC width; 256 threads; thread = 8 rows x (NC/32) cols.
template <int NC, bool RELU>
__global__ __launch_bounds__(256) void k_gemm(const float* __restrict__ A,
                                              const float* __restrict__ W,
                                              const float* __restrict__ bias,
                                              float* __restrict__ C, int M, int K) {
    constexpr int CPT = NC / 32;
    __shared__ float As[32][68];
    __shared__ float Bs[32][NC];
    float acc[8][CPT];
#pragma unroll
    for (int i = 0; i < 8; i++)
#pragma unroll
        for (int j = 0; j < CPT; j++) acc[i][j] = 0.f;

    const int t = threadIdx.x, c = t & 31, rg = t >> 5;
    const int row0 = blockIdx.x * 64;

    for (int k0 = 0; k0 < K; k0 += 32) {
#pragma unroll
        for (int i = 0; i < 2; i++) {
            int fl = t * 2 + i;
            int r = fl >> 3, k4 = fl & 7;
            float4 v = make_float4(0.f, 0.f, 0.f, 0.f);
            int row = row0 + r;
            if (row < M) v = *(const float4*)(A + (size_t)row * K + k0 + k4 * 4);
            As[k4 * 4 + 0][r] = v.x;
            As[k4 * 4 + 1][r] = v.y;
            As[k4 * 4 + 2][r] = v.z;
            As[k4 * 4 + 3][r] = v.w;
        }
#pragma unroll
        for (int i = 0; i < NC / 32; i++) {
            int fl = t + i * 256;
            int kk = fl / (NC / 4), c4 = fl % (NC / 4);
            *(float4*)&Bs[kk][c4 * 4] = *(const float4*)(W + (size_t)(k0 + kk) * NC + c4 * 4);
        }
        __syncthreads();
#pragma unroll
        for (int kk = 0; kk < 32; kk++) {
            float a[8], b[CPT];
            *(float4*)&a[0] = *(const float4*)&As[kk][rg * 8];
            *(float4*)&a[4] = *(const float4*)&As[kk][rg * 8 + 4];
            *(float4*)&b[0] = *(const float4*)&Bs[kk][4 * c];
            if constexpr (CPT == 8) *(float4*)&b[4] = *(const float4*)&Bs[kk][128 + 4 * c];
#pragma unroll
            for (int i = 0; i < 8; i++)
#pragma unroll
                for (int j = 0; j < CPT; j++) acc[i][j] = fmaf(a[i], b[j], acc[i][j]);
        }
        __syncthreads();
    }

#pragma unroll
    for (int i = 0; i < 8; i++) {
        int row = row0 + rg * 8 + i;
        if (row >= M) continue;
        float* crow = C + (size_t)row * NC;
        {
            float o0 = acc[i][0], o1 = acc[i][1], o2 = acc[i][2], o3 = acc[i][3];
            if (bias) {
                o0 += bias[4 * c + 0]; o1 += bias[4 * c + 1];
                o2 += bias[4 * c + 2]; o3 += bias[4 * c + 3];
            }
            if (RELU) {
                o0 = fmaxf(o0, 0.f); o1 = fmaxf(o1, 0.f);
                o2 = fmaxf(o2, 0.f); o3 = fmaxf(o3, 0.f);
            }
            *(float4*)(crow + 4 * c) = make_float4(o0, o1, o2, o3);
        }
        if constexpr (CPT == 8) {
            float o0 = acc[i][4], o1 = acc[i][5], o2 = acc[i][6], o3 = acc[i][7];
            if (bias) {
                o0 += bias[128 + 4 * c + 0]; o1 += bias[128 + 4 * c + 1];
                o2 += bias[128 + 4 * c + 2]; o3 += bias[128 + 4 * c + 3];
            }
            if (RELU) {
                o0 = fmaxf(o0, 0.f); o1 = fmaxf(o1, 0.f);
                o2 = fmaxf(o2, 0.f); o3 = fmaxf(o3, 0.f);
            }
            *(float4*)(crow + 128 + 4 * c) = make_float4(o0, o1, o2, o3);
        }
    }
}

// ---------------- fused edge pre: Eh = conn@WE (K=128, NC=256), epilogue:
// conn_e = relu(signed_sqrt((Qh[dst]+Kh[src])*Ew)+Eb) -> bf16; scoreraw per head.
__global__ __launch_bounds__(256) void k_edge_pre(
    const float* __restrict__ conn, const float* __restrict__ WE,
    const float* __restrict__ Qh, const float* __restrict__ Kh,
    const int* __restrict__ ei, const float* __restrict__ Aw,
    u16* __restrict__ conn_e, float* __restrict__ scoreraw) {
    __shared__ float As[32][68];
    __shared__ float Bs[32][256];
    float acc[8][8];
#pragma unroll
    for (int i = 0; i < 8; i++)
#pragma unroll
        for (int j = 0; j < 8; j++) acc[i][j] = 0.f;

    const int t = threadIdx.x, c = t & 31, rg = t >> 5;
    const int row0 = blockIdx.x * 64;

    for (int k0 = 0; k0 < 128; k0 += 32) {
#pragma unroll
        for (int i = 0; i < 2; i++) {
            int fl = t * 2 + i;
            int r = fl >> 3, k4 = fl & 7;
            float4 v = *(const float4*)(conn + (size_t)(row0 + r) * 128 + k0 + k4 * 4);
            As[k4 * 4 + 0][r] = v.x;
            As[k4 * 4 + 1][r] = v.y;
            As[k4 * 4 + 2][r] = v.z;
            As[k4 * 4 + 3][r] = v.w;
        }
#pragma unroll
        for (int i = 0; i < 8; i++) {
            int fl = t + i * 256;
            int kk = fl / 64, c4 = fl % 64;
            *(float4*)&Bs[kk][c4 * 4] = *(const float4*)(WE + (size_t)(k0 + kk) * 256 + c4 * 4);
        }
        __syncthreads();
#pragma unroll
        for (int kk = 0; kk < 32; kk++) {
            float a[8], b[8];
            *(float4*)&a[0] = *(const float4*)&As[kk][rg * 8];
            *(float4*)&a[4] = *(const float4*)&As[kk][rg * 8 + 4];
            *(float4*)&b[0] = *(const float4*)&Bs[kk][4 * c];
            *(float4*)&b[4] = *(const float4*)&Bs[kk][128 + 4 * c];
#pragma unroll
            for (int i = 0; i < 8; i++)
#pragma unroll
                for (int j = 0; j < 8; j++) acc[i][j] = fmaf(a[i], b[j], acc[i][j]);
        }
        __syncthreads();
    }

    const int h = c >> 2;
    float aw[4];
#pragma unroll
    for (int jj = 0; jj < 4; jj++) aw[jj] = Aw[((4 * c + jj) & 15) * 8 + h];

#pragma unroll
    for (int i = 0; i < 8; i++) {
        int e = row0 + rg * 8 + i;
        int dn = ei[e], sn = ei[NE + e];
        float4 q = *(const float4*)(Qh + (size_t)dn * 128 + 4 * c);
        float4 kv = *(const float4*)(Kh + (size_t)sn * 128 + 4 * c);
        float mv[4] = {q.x + kv.x, q.y + kv.y, q.z + kv.z, q.w + kv.w};
        float ce[4];
        float sp = 0.f;
#pragma unroll
        for (int jj = 0; jj < 4; jj++) {
            float cw = mv[jj] * acc[i][jj];
            float ss = (cw > 0.f) ? sqrtf(cw) : ((cw < 0.f) ? -sqrtf(-cw) : 0.f);
            float v = ss + acc[i][4 + jj];
            v = (v > 0.f) ? v : 0.f;
            ce[jj] = v;
            sp = fmaf(v, aw[jj], sp);
        }
        ushort4 pk;
        pk.x = f2bf(ce[0]); pk.y = f2bf(ce[1]); pk.z = f2bf(ce[2]); pk.w = f2bf(ce[3]);
        *(ushort4*)(conn_e + (size_t)e * 128 + 4 * c) = pk;
        sp += __shfl_xor(sp, 1);
        sp += __shfl_xor(sp, 2);
        if ((c & 3) == 0) {
            sp = fminf(fmaxf(sp, -5.f), 5.f);
            scoreraw[(size_t)e * 8 + h] = sp;
        }
    }
}

// ---------------- per-node gather: softmax over incoming edges, agg/rowV, Bw einsum, deg scale
__global__ void k_gather(const int* __restrict__ ei, const int* __restrict__ rowstart,
                         const int* __restrict__ csr, const float* __restrict__ scoreraw,
                         const u16* __restrict__ conn_e, const float* __restrict__ Vh,
                         const float* __restrict__ Qh, const float* __restrict__ Bw,
                         const float* __restrict__ logdeg, const float* __restrict__ deg_coef,
                         float* __restrict__ tout) {
    int n = blockIdx.x;
    int j = threadIdx.x;  // 0..127
    int h = j >> 4, d = j & 15;
    int rs = rowstart[n], re = rowstart[n + 1];

    float mx = -1e30f;
    for (int p = rs; p < re; p++) {
        int e = csr[p];
        mx = fmaxf(mx, scoreraw[(size_t)e * 8 + h]);
    }
    float ssum = 0.f, aggj = 0.f, rowvj = 0.f;
    for (int p = rs; p < re; p++) {
        int e = csr[p];
        float s = expf(scoreraw[(size_t)e * 8 + h] - mx);
        ssum += s;
        int sn = ei[NE + e];
        aggj = fmaf(Vh[(size_t)sn * 128 + j], s, aggj);
        rowvj = fmaf(bf2f(conn_e[(size_t)e * 128 + j]), s, rowvj);
    }
    float inv = 1.f / (ssum + 1e-16f);
    aggj *= inv;
    rowvj *= inv;

    __shared__ float rv[128];
    rv[j] = rowvj;
    __syncthreads();
    float ro = 0.f;
#pragma unroll
    for (int d2 = 0; d2 < 16; d2++) ro = fmaf(rv[h * 16 + d2], Bw[(d2 * 8 + h) * 16 + d], ro);

    float ha = Qh[(size_t)n * 128 + j] + aggj + ro;
    float ld = logdeg[n];
    tout[(size_t)n * 128 + j] = ha * (deg_coef[2 * j] + ld * deg_coef[2 * j + 1]);
}

// ---------------- LayerNorm(a + b) * g + be  -> out  (rows of 128)
__global__ void k_ln_res(const float* __restrict__ a, const float* __restrict__ b,
                         const float* __restrict__ g, const float* __restrict__ be,
                         float* __restrict__ out, int M) {
    int row = blockIdx.x * 4 + (threadIdx.x >> 6);
    int lane = threadIdx.x & 63;
    if (row >= M) return;
    size_t off = (size_t)row * 128 + lane * 2;
    float v0 = a[off] + b[off];
    float v1 = a[off + 1] + b[off + 1];
    float s = v0 + v1;
#pragma unroll
    for (int m = 1; m < 64; m <<= 1) s += __shfl_xor(s, m);
    float mean = s * (1.f / 128.f);
    float d0 = v0 - mean, d1 = v1 - mean;
    float q = d0 * d0 + d1 * d1;
#pragma unroll
    for (int m = 1; m < 64; m <<= 1) q += __shfl_xor(q, m);
    float rstd = rsqrtf(q * (1.f / 128.f) + 1e-5f);
    out[off] = d0 * rstd * g[lane * 2] + be[lane * 2];
    out[off + 1] = d1 * rstd * g[lane * 2 + 1] + be[lane * 2 + 1];
}

// ---------------- fused edge out: e = LN1e(conn + conn_e@Eo_w + Eo_b)
__global__ __launch_bounds__(256) void k_edge_out(
    const u16* __restrict__ conn_e, const float* __restrict__ Eo_w,
    const float* __restrict__ Eo_b, const float* __restrict__ conn,
    const float* __restrict__ g, const float* __restrict__ be,
    float* __restrict__ eout) {
    __shared__ float As[32][68];
    __shared__ float Bs[32][128];
    float acc[8][4];
#pragma unroll
    for (int i = 0; i < 8; i++)
#pragma unroll
        for (int j = 0; j < 4; j++) acc[i][j] = 0.f;

    const int t = threadIdx.x, c = t & 31, rg = t >> 5;
    const int row0 = blockIdx.x * 64;

    for (int k0 = 0; k0 < 128; k0 += 32) {
#pragma unroll
        for (int i = 0; i < 2; i++) {
            int fl = t * 2 + i;
            int r = fl >> 3, k4 = fl & 7;
            ushort4 u = *(const ushort4*)(conn_e + (size_t)(row0 + r) * 128 + k0 + k4 * 4);
            As[k4 * 4 + 0][r] = bf2f(u.x);
            As[k4 * 4 + 1][r] = bf2f(u.y);
            As[k4 * 4 + 2][r] = bf2f(u.z);
            As[k4 * 4 + 3][r] = bf2f(u.w);
        }
#pragma unroll
        for (int i = 0; i < 4; i++) {
            int fl = t + i * 256;
            int kk = fl >> 5, c4 = fl & 31;
            *(float4*)&Bs[kk][c4 * 4] = *(const float4*)(Eo_w + (size_t)(k0 + kk) * 128 + c4 * 4);
        }
        __syncthreads();
#pragma unroll
        for (int kk = 0; kk < 32; kk++) {
            float a[8], b[4];
            *(float4*)&a[0] = *(const float4*)&As[kk][rg * 8];
            *(float4*)&a[4] = *(const float4*)&As[kk][rg * 8 + 4];
            *(float4*)&b[0] = *(const float4*)&Bs[kk][4 * c];
#pragma unroll
            for (int i = 0; i < 8; i++)
#pragma unroll
                for (int j = 0; j < 4; j++) acc[i][j] = fmaf(a[i], b[j], acc[i][j]);
        }
        __syncthreads();
    }

    float4 eb = *(const float4*)(Eo_b + 4 * c);
    float4 gg = *(const float4*)(g + 4 * c);
    float4 bb = *(const float4*)(be + 4 * c);
#pragma unroll
    for (int i = 0; i < 8; i++) {
        size_t e = (size_t)(row0 + rg * 8 + i);
        float4 cn = *(const float4*)(conn + e * 128 + 4 * c);
        float v0 = acc[i][0] + eb.x + cn.x;
        float v1 = acc[i][1] + eb.y + cn.y;
        float v2 = acc[i][2] + eb.z + cn.z;
        float v3 = acc[i][3] + eb.w + cn.w;
        float s1 = v0 + v1 + v2 + v3;
        float s2 = v0 * v0 + v1 * v1 + v2 * v2 + v3 * v3;
#pragma unroll
        for (int m = 1; m < 32; m <<= 1) {
            s1 += __shfl_xor(s1, m);
            s2 += __shfl_xor(s2, m);
        }
        float mean = s1 * (1.f / 128.f);
        float var = s2 * (1.f / 128.f) - mean * mean;
        float rstd = rsqrtf(var + 1e-5f);
        float4 ov;
        ov.x = (v0 - mean) * rstd * gg.x + bb.x;
        ov.y = (v1 - mean) * rstd * gg.y + bb.y;
        ov.z = (v2 - mean) * rstd * gg.z + bb.z;
        ov.w = (v3 - mean) * rstd * gg.w + bb.w;
        *(float4*)(eout + e * 128 + 4 * c) = ov;
    }
}

extern "C" void kernel_launch(void* const* d_in, const int* in_sizes, int n_in,
                              void* d_out, int out_size, void* d_ws, size_t ws_size,
                              hipStream_t stream) {
    const float* x = (const float*)d_in[0];
    const float* conn = (const float*)d_in[1];
    const float* log_deg = (const float*)d_in[2];
    const int* ei = (const int*)d_in[3];
    const float* WQ = (const float*)d_in[4];
    const float* WK = (const float*)d_in[5];
    const float* WV = (const float*)d_in[6];
    const float* WE = (const float*)d_in[7];
    const float* Aw = (const float*)d_in[8];
    const float* Bw = (const float*)d_in[9];
    const float* Ho_w = (const float*)d_in[10];
    const float* Ho_b = (const float*)d_in[11];
    const float* Eo_w = (const float*)d_in[12];
    const float* Eo_b = (const float*)d_in[13];
    const float* deg_coef = (const float*)d_in[14];
    const float* ln1h_g = (const float*)d_in[15];
    const float* ln1h_b = (const float*)d_in[16];
    const float* ln1e_g = (const float*)d_in[17];
    const float* ln1e_b = (const float*)d_in[18];
    const float* ln2h_g = (const float*)d_in[19];
    const float* ln2h_b = (const float*)d_in[20];
    const float* W1 = (const float*)d_in[21];
    const float* b1 = (const float*)d_in[22];
    const float* W2 = (const float*)d_in[23];
    const float* b2 = (const float*)d_in[24];

    // workspace layout
    float* fbase = (float*)d_ws;
    float* Qh = fbase;
    float* Kh = Qh + (size_t)NN * HIDC;
    float* Vh = Kh + (size_t)NN * HIDC;
    float* tbuf = Vh + (size_t)NN * HIDC;
    float* h1 = tbuf + (size_t)NN * HIDC;
    float* scoreraw = h1 + (size_t)NN * HIDC;
    u16* conn_e = (u16*)(scoreraw + (size_t)NE * NH);
    int* deg = (int*)(conn_e + (size_t)NE * HIDC);
    int* rowstart = deg + NN;
    int* cursor = rowstart + NN + 1;
    int* csr = cursor + NN;
    float* f1 = (float*)conn_e;  // reused after edge_out
    float* u_h = Vh;             // reused after gather
    float* u2 = Qh;              // reused after gather

    float* out_h = (float*)d_out;
    float* out_e = out_h + (size_t)NN * HIDC;

    const int gN64 = (NN + 63) / 64;
    const int gE64 = NE / 64;

    k_init<<<(NN + 255) / 256, 256, 0, stream>>>(deg, cursor);
    k_count<<<(NE + 255) / 256, 256, 0, stream>>>(ei, deg);
    k_scan<<<1, 1024, 0, stream>>>(deg, rowstart);
    k_fill<<<(NE + 255) / 256, 256, 0, stream>>>(ei, rowstart, cursor, csr);

    k_gemm<128, false><<<gN64, 256, 0, stream>>>(x, WQ, nullptr, Qh, NN, 128);
    k_gemm<128, false><<<gN64, 256, 0, stream>>>(x, WK, nullptr, Kh, NN, 128);
    k_gemm<128, false><<<gN64, 256, 0, stream>>>(x, WV, nullptr, Vh, NN, 128);

    k_edge_pre<<<gE64, 256, 0, stream>>>(conn, WE, Qh, Kh, ei, Aw, conn_e, scoreraw);

    k_gather<<<NN, 128, 0, stream>>>(ei, rowstart, csr, scoreraw, conn_e, Vh, Qh, Bw,
                                     log_deg, deg_coef, tbuf);

    k_gemm<128, false><<<gN64, 256, 0, stream>>>(tbuf, Ho_w, Ho_b, u_h, NN, 128);
    k_ln_res<<<(NN + 3) / 4, 256, 0, stream>>>(u_h, x, ln1h_g, ln1h_b, h1, NN);

    k_edge_out<<<gE64, 256, 0, stream>>>(conn_e, Eo_w, Eo_b, conn, ln1e_g, ln1e_b, out_e);

    k_gemm<256, true><<<gN64, 256, 0, stream>>>(h1, W1, b1, f1, NN, 128);
    k_gemm<128, false><<<gN64, 256, 0, stream>>>(f1, W2, b2, u2, NN, 256);
    k_ln_res<<<(NN + 3) / 4, 256, 0, stream>>>(u2, h1, ln2h_g, ln2h_b, out_h, NN);
}